// Round 13
// baseline (411.435 us; speedup 1.0000x reference)
//
#include <hip/hip_runtime.h>
#include <math.h>

#define NN 20000      // nodes
#define NE 320000     // edges
#define NG 64         // graphs
#define IND 128
#define HIDD 256
#define NH 4
#define ED 5
#define NACT 8
#define NEG 0.2f
#define MAXDEG 64

// ---------------- fp32 GEMM, 64x64 tile, BK=32, 4x4 per thread ----------------
// Grid (313,4,2) = 2504 blocks (~9.8/CU) fixes R12's grid-starved 30% occupancy.
// float4 staging (R8-proven); launch_bounds(256,8) -> VGPR<=64, 8 blocks/CU target.
__global__ __launch_bounds__(256, 8) void gemm64v2(
    const float* __restrict__ A, const float* __restrict__ Bl,
    const float* __restrict__ Br, float* __restrict__ Cl, float* __restrict__ Cr,
    int M, int K, int Ncol)
{
    const float* B = blockIdx.z ? Br : Bl;
    float*       C = blockIdx.z ? Cr : Cl;
    __shared__ float As[32][65];   // [k][m], pad 65 -> conflict-light
    __shared__ float Bs[32][64];   // [k][n]
    int bm = blockIdx.x * 64, bn = blockIdx.y * 64;
    int tid = threadIdx.x;
    int tx = tid & 15, ty = tid >> 4;
    float acc[4][4] = {};
    for (int k0 = 0; k0 < K; k0 += 32) {
        // A tile: 64 rows x 32 k = 512 float4; 2 per thread
        #pragma unroll
        for (int t = 0; t < 2; ++t) {
            int idx = tid + t * 256;          // 0..511
            int r = idx >> 3;                 // row (8 float4 per row)
            int c4 = (idx & 7) * 4;           // k offset
            int gr = bm + r;
            float4 v = {0.f, 0.f, 0.f, 0.f};
            if (gr < M) v = *(const float4*)&A[gr * K + k0 + c4];
            As[c4 + 0][r] = v.x;
            As[c4 + 1][r] = v.y;
            As[c4 + 2][r] = v.z;
            As[c4 + 3][r] = v.w;
        }
        // B tile: 32 k x 64 n = 512 float4; 2 per thread
        #pragma unroll
        for (int t = 0; t < 2; ++t) {
            int idx = tid + t * 256;          // 0..511
            int r = idx >> 4;                 // k row (16 float4 per row)
            int c4 = (idx & 15) * 4;          // n offset
            float4 v = *(const float4*)&B[(k0 + r) * Ncol + bn + c4];
            *(float4*)&Bs[r][c4] = v;
        }
        __syncthreads();
        #pragma unroll
        for (int k = 0; k < 32; ++k) {
            float4 a4 = *(const float4*)&As[k][ty * 4];
            float4 b4 = *(const float4*)&Bs[k][tx * 4];
            float a[4] = {a4.x, a4.y, a4.z, a4.w};
            float b[4] = {b4.x, b4.y, b4.z, b4.w};
            #pragma unroll
            for (int i = 0; i < 4; ++i)
                #pragma unroll
                for (int j = 0; j < 4; ++j)
                    acc[i][j] = fmaf(a[i], b[j], acc[i][j]);
        }
        __syncthreads();
    }
    #pragma unroll
    for (int i = 0; i < 4; ++i) {
        int r = bm + ty * 4 + i;
        if (r < M) {
            float4 v = {acc[i][0], acc[i][1], acc[i][2], acc[i][3]};
            *(float4*)&C[r * Ncol + bn + tx * 4] = v;
        }
    }
}

// ---------------- inverse adjacency: per-dst fixed slots ----------------
__global__ __launch_bounds__(256) void build_slots(const int* __restrict__ dst,
    int* __restrict__ deg, int* __restrict__ slots)
{
    int e = blockIdx.x * 256 + threadIdx.x;
    if (e >= NE) return;
    int d = dst[e];
    int pos = atomicAdd(&deg[d], 1);
    if (pos < MAXDEG) slots[d * MAXDEG + pos] = e;
}

// ---------------- FUSED layer: one wave per block per node (R12-proven) ----------------
// int32 offset arithmetic throughout (max offset ~5.1M): no 64-bit mul chains.
template <int HEADS_T>
__global__ __launch_bounds__(64) void fused_agg(
    const int* __restrict__ deg, const int* __restrict__ slots,
    const int* __restrict__ src, const float* __restrict__ eattr,
    const float* __restrict__ xl, const float* __restrict__ xr,
    const float* __restrict__ We, const float* __restrict__ attw,
    const float* __restrict__ bias, float* __restrict__ out)
{
    int lane = threadIdx.x;
    int n = blockIdx.x;
    int c0 = lane * 4;

    int dg = min(deg[n], MAXDEG);
    const int* slotrow = slots + n * MAXDEG;

    float attr_[4], wer[ED][4];
    #pragma unroll
    for (int j = 0; j < 4; ++j) attr_[j] = attw[c0 + j];
    #pragma unroll
    for (int k = 0; k < ED; ++k)
        #pragma unroll
        for (int j = 0; j < 4; ++j) wer[k][j] = We[k * HIDD + c0 + j];

    float4 xr4 = *(const float4*)(xr + n * HIDD + c0);
    float xra[4] = {xr4.x, xr4.y, xr4.z, xr4.w};

    float denom = 0.f;
    float acc[4] = {0.f, 0.f, 0.f, 0.f};

    for (int i = 0; i < dg; ++i) {
        int e = slotrow[i];
        int s = src[e];
        float4 xl4 = *(const float4*)(xl + s * HIDD + c0);
        float xla[4] = {xl4.x, xl4.y, xl4.z, xl4.w};
        float ea[ED];
        #pragma unroll
        for (int k = 0; k < ED; ++k) ea[k] = eattr[e * ED + k];
        float partial = 0.f;
        #pragma unroll
        for (int j = 0; j < 4; ++j) {
            float ev = 0.f;
            #pragma unroll
            for (int k = 0; k < ED; ++k) ev = fmaf(ea[k], wer[k][j], ev);
            float m = xla[j] + xra[j] + ev;
            m = m > 0.f ? m : NEG * m;
            partial = fmaf(m, attr_[j], partial);
        }
        if (HEADS_T == 4) {
            #pragma unroll
            for (int off = 1; off < 16; off <<= 1)
                partial += __shfl_xor(partial, off, 64);
        } else {
            #pragma unroll
            for (int off = 1; off < 64; off <<= 1)
                partial += __shfl_xor(partial, off, 64);
        }
        float ex = expf(partial);
        denom += ex;
        #pragma unroll
        for (int j = 0; j < 4; ++j) acc[j] = fmaf(ex, xla[j], acc[j]);
    }

    float inv = 1.f / (denom + 1e-16f);
    float4 o;
    o.x = fmaxf(acc[0] * inv + bias[c0 + 0], 0.f);
    o.y = fmaxf(acc[1] * inv + bias[c0 + 1], 0.f);
    o.z = fmaxf(acc[2] * inv + bias[c0 + 2], 0.f);
    o.w = fmaxf(acc[3] * inv + bias[c0 + 3], 0.f);
    *(float4*)(out + n * HIDD + c0) = o;
}

// ---------------- global mean pool (batch is sorted) ----------------
#define POOL_CHUNK 128
__global__ __launch_bounds__(256) void pool_kernel(
    const float* __restrict__ h, const int* __restrict__ batch,
    float* __restrict__ pool, float* __restrict__ cnt)
{
    int c = threadIdx.x;
    int start = blockIdx.x * POOL_CHUNK;
    int end = min(start + POOL_CHUNK, NN);
    if (start >= NN) return;
    float acc = 0.f;
    int cur = batch[start];
    int localCount = 0;
    for (int n = start; n < end; ++n) {
        int g = batch[n];
        if (g != cur) {
            atomicAdd(&pool[cur * HIDD + c], acc);
            if (c == 0) atomicAdd(&cnt[cur], (float)localCount);
            acc = 0.f; localCount = 0; cur = g;
        }
        acc += h[n * HIDD + c];
        ++localCount;
    }
    atomicAdd(&pool[cur * HIDD + c], acc);
    if (c == 0) atomicAdd(&cnt[cur], (float)localCount);
}

// ---------------- heads: logits [G,8] and value [G], out [G,9] ----------------
__global__ __launch_bounds__(256) void head_kernel(
    const float* __restrict__ pool, const float* __restrict__ cnt,
    const float* __restrict__ Wp, const float* __restrict__ bp,
    const float* __restrict__ Wv, const float* __restrict__ bv,
    float* __restrict__ out)
{
    int g = blockIdx.x;
    int c = threadIdx.x;
    float gv = pool[g * HIDD + c] / fmaxf(cnt[g], 1.0f);
    __shared__ float red[256];
    for (int j = 0; j < NACT + 1; ++j) {
        float w = (j < NACT) ? Wp[c * NACT + j] : Wv[c];
        red[c] = gv * w;
        __syncthreads();
        for (int sl = 128; sl > 0; sl >>= 1) {
            if (c < sl) red[c] += red[c + sl];
            __syncthreads();
        }
        if (c == 0) out[g * (NACT + 1) + j] = red[0] + ((j < NACT) ? bp[j] : bv[0]);
        __syncthreads();
    }
}

extern "C" void kernel_launch(void* const* d_in, const int* in_sizes, int n_in,
                              void* d_out, int out_size, void* d_ws, size_t ws_size,
                              hipStream_t stream)
{
    const float* x    = (const float*)d_in[0];
    const int*   ei   = (const int*)d_in[1];
    const int*   batch= (const int*)d_in[2];
    const float* ea   = (const float*)d_in[3];
    const float* W1l  = (const float*)d_in[4];
    const float* W1r  = (const float*)d_in[5];
    const float* W1e  = (const float*)d_in[6];
    const float* att1 = (const float*)d_in[7];
    const float* b1   = (const float*)d_in[8];
    const float* W2l  = (const float*)d_in[9];
    const float* W2r  = (const float*)d_in[10];
    const float* W2e  = (const float*)d_in[11];
    const float* att2 = (const float*)d_in[12];
    const float* b2   = (const float*)d_in[13];
    const float* Wp   = (const float*)d_in[14];
    const float* bp   = (const float*)d_in[15];
    const float* Wv   = (const float*)d_in[16];
    const float* bv   = (const float*)d_in[17];
    const int* src = ei;
    const int* dst = ei + NE;
    float* out = (float*)d_out;

    // workspace layout (floats)
    float* ws = (float*)d_ws;
    size_t off = 0;
    float* A     = ws + off; off += (size_t)NN * HIDD;   // xl (layer 1 then layer 2)
    float* B     = ws + off; off += (size_t)NN * HIDD;   // xr (layer 1 then layer 2)
    float* C     = ws + off; off += (size_t)NN * HIDD;   // h1
    float* D     = ws + off; off += (size_t)NN * HIDD;   // h2
    float* pool  = ws + off; off += (size_t)NG * HIDD;
    float* cnt   = ws + off; off += NG;
    int*   deg   = (int*)(ws + off); off += NN;
    int*   slots = (int*)(ws + off); off += (size_t)NN * MAXDEG;

    // zero: pool, cnt, deg (contiguous region)
    hipMemsetAsync(pool, 0, (size_t)(NG * HIDD + NG + NN) * sizeof(float), stream);

    // inverse adjacency
    build_slots<<<(NE + 255) / 256, 256, 0, stream>>>(dst, deg, slots);

    // ---- layer 1 ----
    dim3 g1((NN + 63) / 64, HIDD / 64, 2);
    gemm64v2<<<g1, 256, 0, stream>>>(x, W1l, W1r, A, B, NN, IND, HIDD);
    fused_agg<4><<<NN, 64, 0, stream>>>(deg, slots, src, ea, A, B, W1e, att1, b1, C);

    // ---- layer 2 ----
    gemm64v2<<<g1, 256, 0, stream>>>(C, W2l, W2r, A, B, NN, HIDD, HIDD);
    fused_agg<1><<<NN, 64, 0, stream>>>(deg, slots, src, ea, A, B, W2e, att2, b2, D);

    // ---- pool + heads ----
    pool_kernel<<<(NN + POOL_CHUNK - 1) / POOL_CHUNK, 256, 0, stream>>>(D, batch, pool, cnt);
    head_kernel<<<NG, 256, 0, stream>>>(pool, cnt, Wp, bp, Wv, bv, out);
}

// Round 18
// 407.347 us; speedup vs baseline: 1.0100x; 1.0100x over previous
//
#include <hip/hip_runtime.h>
#include <math.h>

#define NN 20000      // nodes
#define NE 320000     // edges
#define NG 64         // graphs
#define IND 128
#define HIDD 256
#define NH 4
#define ED 5
#define NACT 8
#define NEG 0.2f
#define MAXDEG 64

// ---------------- fp32 GEMM, 128x128 tile, BK=16, 8x8 per thread ----------------
// R13 post-mortem: 4x4 micro-tile = 1.0 B(LDS)/FLOP -> LDS-read roofline at ~84us.
// 8x8 micro-tile = 0.5 B/FLOP. Cols/rows split as {q*4, 64+q*4} so B LDS reads are
// 2-way bank-aliased (free, m136) instead of 4-way. blockIdx.z selects l/r matrix.
__global__ __launch_bounds__(256, 4) void gemm128x128(
    const float* __restrict__ A, const float* __restrict__ Bl,
    const float* __restrict__ Br, float* __restrict__ Cl, float* __restrict__ Cr,
    int M, int K, int Ncol)
{
    const float* B = blockIdx.z ? Br : Bl;
    float*       C = blockIdx.z ? Cr : Cl;
    __shared__ float As[16][132];   // [k][m], LD=132 -> write aliasing 2-way (free)
    __shared__ float Bs[16][128];   // [k][n]
    int bm = blockIdx.x * 128, bn = blockIdx.y * 128;
    int tid = threadIdx.x;
    int tx = tid & 15, ty = tid >> 4;
    float acc[8][8] = {};
    for (int k0 = 0; k0 < K; k0 += 16) {
        // A tile: 128 rows x 16 k = 512 float4 (4 k each); 2 per thread
        #pragma unroll
        for (int t = 0; t < 2; ++t) {
            int idx = tid + t * 256;          // 0..511
            int r = idx >> 2;                 // row (4 float4 per row)
            int c4 = (idx & 3) * 4;           // k offset
            int gr = bm + r;
            float4 v = {0.f, 0.f, 0.f, 0.f};
            if (gr < M) v = *(const float4*)&A[gr * K + k0 + c4];
            As[c4 + 0][r] = v.x;
            As[c4 + 1][r] = v.y;
            As[c4 + 2][r] = v.z;
            As[c4 + 3][r] = v.w;
        }
        // B tile: 16 k x 128 n = 512 float4; 2 per thread (coalesced)
        #pragma unroll
        for (int t = 0; t < 2; ++t) {
            int idx = tid + t * 256;          // 0..511
            int r = idx >> 5;                 // k row (32 float4 per row)
            int c4 = (idx & 31) * 4;          // n offset
            float4 v = *(const float4*)&B[(k0 + r) * Ncol + bn + c4];
            *(float4*)&Bs[r][c4] = v;
        }
        __syncthreads();
        #pragma unroll
        for (int k = 0; k < 16; ++k) {
            float4 a0 = *(const float4*)&As[k][ty * 4];
            float4 a1 = *(const float4*)&As[k][64 + ty * 4];
            float4 b0 = *(const float4*)&Bs[k][tx * 4];
            float4 b1 = *(const float4*)&Bs[k][64 + tx * 4];
            float a[8] = {a0.x, a0.y, a0.z, a0.w, a1.x, a1.y, a1.z, a1.w};
            float b[8] = {b0.x, b0.y, b0.z, b0.w, b1.x, b1.y, b1.z, b1.w};
            #pragma unroll
            for (int i = 0; i < 8; ++i)
                #pragma unroll
                for (int j = 0; j < 8; ++j)
                    acc[i][j] = fmaf(a[i], b[j], acc[i][j]);
        }
        __syncthreads();
    }
    #pragma unroll
    for (int i = 0; i < 8; ++i) {
        int r = bm + ((i < 4) ? (ty * 4 + i) : (64 + ty * 4 + i - 4));
        if (r < M) {
            float4 v0 = {acc[i][0], acc[i][1], acc[i][2], acc[i][3]};
            float4 v1 = {acc[i][4], acc[i][5], acc[i][6], acc[i][7]};
            *(float4*)&C[r * Ncol + bn + tx * 4] = v0;
            *(float4*)&C[r * Ncol + bn + 64 + tx * 4] = v1;
        }
    }
}

// ---------------- inverse adjacency: per-dst fixed slots ----------------
__global__ __launch_bounds__(256) void build_slots(const int* __restrict__ dst,
    int* __restrict__ deg, int* __restrict__ slots)
{
    int e = blockIdx.x * 256 + threadIdx.x;
    if (e >= NE) return;
    int d = dst[e];
    int pos = atomicAdd(&deg[d], 1);
    if (pos < MAXDEG) slots[d * MAXDEG + pos] = e;
}

// ---------------- FUSED layer: one wave per block per node (R12-proven) ----------------
template <int HEADS_T>
__global__ __launch_bounds__(64) void fused_agg(
    const int* __restrict__ deg, const int* __restrict__ slots,
    const int* __restrict__ src, const float* __restrict__ eattr,
    const float* __restrict__ xl, const float* __restrict__ xr,
    const float* __restrict__ We, const float* __restrict__ attw,
    const float* __restrict__ bias, float* __restrict__ out)
{
    int lane = threadIdx.x;
    int n = blockIdx.x;
    int c0 = lane * 4;

    int dg = min(deg[n], MAXDEG);
    const int* slotrow = slots + n * MAXDEG;

    float attr_[4], wer[ED][4];
    #pragma unroll
    for (int j = 0; j < 4; ++j) attr_[j] = attw[c0 + j];
    #pragma unroll
    for (int k = 0; k < ED; ++k)
        #pragma unroll
        for (int j = 0; j < 4; ++j) wer[k][j] = We[k * HIDD + c0 + j];

    float4 xr4 = *(const float4*)(xr + n * HIDD + c0);
    float xra[4] = {xr4.x, xr4.y, xr4.z, xr4.w};

    float denom = 0.f;
    float acc[4] = {0.f, 0.f, 0.f, 0.f};

    for (int i = 0; i < dg; ++i) {
        int e = slotrow[i];
        int s = src[e];
        float4 xl4 = *(const float4*)(xl + s * HIDD + c0);
        float xla[4] = {xl4.x, xl4.y, xl4.z, xl4.w};
        float ea[ED];
        #pragma unroll
        for (int k = 0; k < ED; ++k) ea[k] = eattr[e * ED + k];
        float partial = 0.f;
        #pragma unroll
        for (int j = 0; j < 4; ++j) {
            float ev = 0.f;
            #pragma unroll
            for (int k = 0; k < ED; ++k) ev = fmaf(ea[k], wer[k][j], ev);
            float m = xla[j] + xra[j] + ev;
            m = m > 0.f ? m : NEG * m;
            partial = fmaf(m, attr_[j], partial);
        }
        if (HEADS_T == 4) {
            #pragma unroll
            for (int off = 1; off < 16; off <<= 1)
                partial += __shfl_xor(partial, off, 64);
        } else {
            #pragma unroll
            for (int off = 1; off < 64; off <<= 1)
                partial += __shfl_xor(partial, off, 64);
        }
        float ex = expf(partial);
        denom += ex;
        #pragma unroll
        for (int j = 0; j < 4; ++j) acc[j] = fmaf(ex, xla[j], acc[j]);
    }

    float inv = 1.f / (denom + 1e-16f);
    float4 o;
    o.x = fmaxf(acc[0] * inv + bias[c0 + 0], 0.f);
    o.y = fmaxf(acc[1] * inv + bias[c0 + 1], 0.f);
    o.z = fmaxf(acc[2] * inv + bias[c0 + 2], 0.f);
    o.w = fmaxf(acc[3] * inv + bias[c0 + 3], 0.f);
    *(float4*)(out + n * HIDD + c0) = o;
}

// ---------------- global mean pool (batch is sorted) ----------------
#define POOL_CHUNK 128
__global__ __launch_bounds__(256) void pool_kernel(
    const float* __restrict__ h, const int* __restrict__ batch,
    float* __restrict__ pool, float* __restrict__ cnt)
{
    int c = threadIdx.x;
    int start = blockIdx.x * POOL_CHUNK;
    int end = min(start + POOL_CHUNK, NN);
    if (start >= NN) return;
    float acc = 0.f;
    int cur = batch[start];
    int localCount = 0;
    for (int n = start; n < end; ++n) {
        int g = batch[n];
        if (g != cur) {
            atomicAdd(&pool[cur * HIDD + c], acc);
            if (c == 0) atomicAdd(&cnt[cur], (float)localCount);
            acc = 0.f; localCount = 0; cur = g;
        }
        acc += h[n * HIDD + c];
        ++localCount;
    }
    atomicAdd(&pool[cur * HIDD + c], acc);
    if (c == 0) atomicAdd(&cnt[cur], (float)localCount);
}

// ---------------- heads: logits [G,8] and value [G], out [G,9] ----------------
__global__ __launch_bounds__(256) void head_kernel(
    const float* __restrict__ pool, const float* __restrict__ cnt,
    const float* __restrict__ Wp, const float* __restrict__ bp,
    const float* __restrict__ Wv, const float* __restrict__ bv,
    float* __restrict__ out)
{
    int g = blockIdx.x;
    int c = threadIdx.x;
    float gv = pool[g * HIDD + c] / fmaxf(cnt[g], 1.0f);
    __shared__ float red[256];
    for (int j = 0; j < NACT + 1; ++j) {
        float w = (j < NACT) ? Wp[c * NACT + j] : Wv[c];
        red[c] = gv * w;
        __syncthreads();
        for (int sl = 128; sl > 0; sl >>= 1) {
            if (c < sl) red[c] += red[c + sl];
            __syncthreads();
        }
        if (c == 0) out[g * (NACT + 1) + j] = red[0] + ((j < NACT) ? bp[j] : bv[0]);
        __syncthreads();
    }
}

extern "C" void kernel_launch(void* const* d_in, const int* in_sizes, int n_in,
                              void* d_out, int out_size, void* d_ws, size_t ws_size,
                              hipStream_t stream)
{
    const float* x    = (const float*)d_in[0];
    const int*   ei   = (const int*)d_in[1];
    const int*   batch= (const int*)d_in[2];
    const float* ea   = (const float*)d_in[3];
    const float* W1l  = (const float*)d_in[4];
    const float* W1r  = (const float*)d_in[5];
    const float* W1e  = (const float*)d_in[6];
    const float* att1 = (const float*)d_in[7];
    const float* b1   = (const float*)d_in[8];
    const float* W2l  = (const float*)d_in[9];
    const float* W2r  = (const float*)d_in[10];
    const float* W2e  = (const float*)d_in[11];
    const float* att2 = (const float*)d_in[12];
    const float* b2   = (const float*)d_in[13];
    const float* Wp   = (const float*)d_in[14];
    const float* bp   = (const float*)d_in[15];
    const float* Wv   = (const float*)d_in[16];
    const float* bv   = (const float*)d_in[17];
    const int* src = ei;
    const int* dst = ei + NE;
    float* out = (float*)d_out;

    // workspace layout (floats)
    float* ws = (float*)d_ws;
    size_t off = 0;
    float* A     = ws + off; off += (size_t)NN * HIDD;   // xl (layer 1 then layer 2)
    float* B     = ws + off; off += (size_t)NN * HIDD;   // xr (layer 1 then layer 2)
    float* C     = ws + off; off += (size_t)NN * HIDD;   // h1
    float* D     = ws + off; off += (size_t)NN * HIDD;   // h2
    float* pool  = ws + off; off += (size_t)NG * HIDD;
    float* cnt   = ws + off; off += NG;
    int*   deg   = (int*)(ws + off); off += NN;
    int*   slots = (int*)(ws + off); off += (size_t)NN * MAXDEG;

    // zero: pool, cnt, deg (contiguous region)
    hipMemsetAsync(pool, 0, (size_t)(NG * HIDD + NG + NN) * sizeof(float), stream);

    // inverse adjacency
    build_slots<<<(NE + 255) / 256, 256, 0, stream>>>(dst, deg, slots);

    // ---- layer 1 ----
    dim3 g1((NN + 127) / 128, HIDD / 128, 2);
    gemm128x128<<<g1, 256, 0, stream>>>(x, W1l, W1r, A, B, NN, IND, HIDD);
    fused_agg<4><<<NN, 64, 0, stream>>>(deg, slots, src, ea, A, B, W1e, att1, b1, C);

    // ---- layer 2 ----
    gemm128x128<<<g1, 256, 0, stream>>>(C, W2l, W2r, A, B, NN, HIDD, HIDD);
    fused_agg<1><<<NN, 64, 0, stream>>>(deg, slots, src, ea, A, B, W2e, att2, b2, D);

    // ---- pool + heads ----
    pool_kernel<<<(NN + POOL_CHUNK - 1) / POOL_CHUNK, 256, 0, stream>>>(D, batch, pool, cnt);
    head_kernel<<<NG, 256, 0, stream>>>(pool, cnt, Wp, bp, Wv, bv, out);
}